// Round 2
// baseline (341.807 us; speedup 1.0000x reference)
//
#include <hip/hip_runtime.h>

// out = sum(left @ weight) + bias
//   left:   (8192, 4096) f32
//   weight: (4096, 4096) f32
// Factorization: sum(L@W) = sum_{i,k} L[i,k] * rowsum(W)[k]
// K1: rowsum(W)  -- one row per wave, shuffle-only, no barriers
// K2: weighted stream of L, one atomicAdd per block, last block writes out.

#define DIM 4096
#define M_ROWS 8192

constexpr int K2_BLOCKS = 2048;          // 512 chunks x 4 col-blocks
constexpr int K2_ROWS = 16;              // rows per chunk (512*16 = 8192)

struct Ws { float acc; unsigned cnt; };

// K1: rowsum of weight. 1024 blocks x 256 threads; wave w of block b owns
// row b*4+w (4096 floats, 16 float4 passes). Also zeroes the accumulator.
__global__ __launch_bounds__(256) void k_rowsum(const float* __restrict__ w,
                                                float* __restrict__ rowsum,
                                                Ws* __restrict__ ws)
{
    if (blockIdx.x == 0 && threadIdx.x == 0) { ws->acc = 0.f; ws->cnt = 0u; }
    const int wave = threadIdx.x >> 6, lane = threadIdx.x & 63;
    const int row = blockIdx.x * 4 + wave;
    const float* p = w + (long)row * DIM;
    float4 a = make_float4(0.f, 0.f, 0.f, 0.f);
    #pragma unroll
    for (int i = 0; i < 16; ++i) {
        const float4 v = *reinterpret_cast<const float4*>(p + (i * 64 + lane) * 4);
        a.x += v.x; a.y += v.y; a.z += v.z; a.w += v.w;
    }
    float s = a.x + a.y + a.z + a.w;
    #pragma unroll
    for (int off = 32; off > 0; off >>= 1) s += __shfl_down(s, off);
    if (lane == 0) rowsum[row] = s;
}

// K2: acc += sum_{i in chunk} L[i, col..col+3] . rowsum[col..col+3]
// Each thread's 4 columns are fixed -> rowsum hoisted to registers once.
// 2048 blocks (8/CU, 32 waves/CU). One atomicAdd per block; counter-based
// last-block writes out = acc + bias.
__global__ __launch_bounds__(256, 8) void k_wsum(const float* __restrict__ l,
                                                 const float* __restrict__ rowsum,
                                                 const float* __restrict__ bias,
                                                 float* __restrict__ out,
                                                 Ws* __restrict__ ws)
{
    __shared__ float red[4];
    const int t = threadIdx.x;
    const int cb = blockIdx.x & 3;          // column block (1024 cols)
    const int chunk = blockIdx.x >> 2;      // 0..511
    const int col = cb * 1024 + t * 4;
    const float4 rw = *reinterpret_cast<const float4*>(rowsum + col);
    const float* p = l + (long)chunk * K2_ROWS * DIM + col;
    float4 a = make_float4(0.f, 0.f, 0.f, 0.f);
    #pragma unroll
    for (int r = 0; r < K2_ROWS; ++r) {
        const float4 v = *reinterpret_cast<const float4*>(p + (long)r * DIM);
        a.x += v.x * rw.x; a.y += v.y * rw.y;
        a.z += v.z * rw.z; a.w += v.w * rw.w;
    }
    float s = a.x + a.y + a.z + a.w;
    #pragma unroll
    for (int off = 32; off > 0; off >>= 1) s += __shfl_down(s, off);
    const int wave = t >> 6, lane = t & 63;
    if (lane == 0) red[wave] = s;
    __syncthreads();
    if (t == 0) {
        const float bs = red[0] + red[1] + red[2] + red[3];
        atomicAdd(&ws->acc, bs);
        __threadfence();
        const unsigned old = atomicAdd(&ws->cnt, 1u);
        if (old == (unsigned)(K2_BLOCKS - 1)) {
            // fresh device-scope read via returns-old RMW
            const float tot = atomicAdd(&ws->acc, 0.0f);
            out[0] = tot + bias[0];
        }
    }
}

extern "C" void kernel_launch(void* const* d_in, const int* in_sizes, int n_in,
                              void* d_out, int out_size, void* d_ws, size_t ws_size,
                              hipStream_t stream) {
    const float* left   = (const float*)d_in[0];
    const float* weight = (const float*)d_in[1];
    const float* bias   = (const float*)d_in[2];
    float* out = (float*)d_out;

    // ws layout: Ws header | rowsum[4096]
    Ws* ws = (Ws*)d_ws;
    float* rowsum = (float*)d_ws + 16;   // 64B-aligned past the header

    k_rowsum<<<DIM / 4, 256, 0, stream>>>(weight, rowsum, ws);
    k_wsum<<<K2_BLOCKS, 256, 0, stream>>>(left, rowsum, bias, out, ws);
}

// Round 3
// 233.860 us; speedup vs baseline: 1.4616x; 1.4616x over previous
//
#include <hip/hip_runtime.h>

// out = sum(left @ weight) + bias
//   left:   (8192, 4096) f32   weight: (4096, 4096) f32
// Factorization: sum(L@W) = sum_{i,k} L[i,k] * rowsum(W)[k]
// K1: half-row sums of W (wave-per-half-row, shuffle-only, plain stores)
// K2: weighted stream of L, ONE plain store per block (no atomics/fences)
// K3: 1-block reduce of 2048 partials + bias

#define DIM 4096

constexpr int K2_BLOCKS = 2048;   // 512 chunks x 4 col-blocks
constexpr int K2_ROWS = 16;       // 512*16 = 8192 rows of left

// K1: 2048 blocks x 256 thr. Wave w of block b owns half-row id = b*4+w
// (2048 floats). Writes rsh[id]; K2 folds the two halves per row.
__global__ __launch_bounds__(256) void k_rowsum(const float* __restrict__ wt,
                                                float* __restrict__ rsh)
{
    const int wave = threadIdx.x >> 6, lane = threadIdx.x & 63;
    const int id = blockIdx.x * 4 + wave;        // 0..8191
    const int row = id >> 1, half = id & 1;
    const float* p = wt + (long)row * DIM + half * 2048;
    float4 a = make_float4(0.f, 0.f, 0.f, 0.f);
    #pragma unroll
    for (int i = 0; i < 8; ++i) {
        const float4 v = *reinterpret_cast<const float4*>(p + (i * 64 + lane) * 4);
        a.x += v.x; a.y += v.y; a.z += v.z; a.w += v.w;
    }
    float s = a.x + a.y + a.z + a.w;
    #pragma unroll
    for (int off = 32; off > 0; off >>= 1) s += __shfl_down(s, off);
    if (lane == 0) rsh[id] = s;
}

// K2: acc += sum_{rows in chunk} L[i, col..col+3] . rw, rw hoisted once.
// 2048 blocks (8/CU). Ends with a single plain store per block.
__global__ __launch_bounds__(256, 8) void k_wsum(const float* __restrict__ l,
                                                 const float* __restrict__ rsh,
                                                 float* __restrict__ bp)
{
    __shared__ float red[4];
    const int t = threadIdx.x;
    const int cb = blockIdx.x & 3;          // column block (1024 cols)
    const int chunk = blockIdx.x >> 2;      // 0..511
    const int col = cb * 1024 + t * 4;
    // per-row weight = sum of the two half-row sums (contiguous pair load)
    const float4* rshv = reinterpret_cast<const float4*>(rsh);
    const float4 v0 = rshv[cb * 512 + t * 2];
    const float4 v1 = rshv[cb * 512 + t * 2 + 1];
    const float4 rw = make_float4(v0.x + v0.y, v0.z + v0.w,
                                  v1.x + v1.y, v1.z + v1.w);
    const float* p = l + (long)chunk * K2_ROWS * DIM + col;
    float4 a = make_float4(0.f, 0.f, 0.f, 0.f);
    #pragma unroll
    for (int r = 0; r < K2_ROWS; ++r) {
        const float4 v = *reinterpret_cast<const float4*>(p + (long)r * DIM);
        a.x += v.x * rw.x; a.y += v.y * rw.y;
        a.z += v.z * rw.z; a.w += v.w * rw.w;
    }
    float s = a.x + a.y + a.z + a.w;
    #pragma unroll
    for (int off = 32; off > 0; off >>= 1) s += __shfl_down(s, off);
    const int wave = t >> 6, lane = t & 63;
    if (lane == 0) red[wave] = s;
    __syncthreads();
    if (t == 0) bp[blockIdx.x] = red[0] + red[1] + red[2] + red[3];
}

// K3: reduce 2048 block partials + bias.
__global__ __launch_bounds__(256) void k_final(const float* __restrict__ bp,
                                               const float* __restrict__ bias,
                                               float* __restrict__ out)
{
    __shared__ float red[4];
    const int t = threadIdx.x;
    float s = 0.f;
    #pragma unroll
    for (int i = 0; i < 8; ++i) s += bp[t + i * 256];
    #pragma unroll
    for (int off = 32; off > 0; off >>= 1) s += __shfl_down(s, off);
    if ((t & 63) == 0) red[t >> 6] = s;
    __syncthreads();
    if (t == 0) out[0] = red[0] + red[1] + red[2] + red[3] + bias[0];
}

extern "C" void kernel_launch(void* const* d_in, const int* in_sizes, int n_in,
                              void* d_out, int out_size, void* d_ws, size_t ws_size,
                              hipStream_t stream) {
    const float* left   = (const float*)d_in[0];
    const float* weight = (const float*)d_in[1];
    const float* bias   = (const float*)d_in[2];
    float* out = (float*)d_out;

    // ws layout: rsh[8192] f32 | bp[2048] f32
    float* rsh = (float*)d_ws;
    float* bp  = rsh + 8192;

    k_rowsum<<<2048, 256, 0, stream>>>(weight, rsh);
    k_wsum  <<<K2_BLOCKS, 256, 0, stream>>>(left, rsh, bp);
    k_final <<<1, 256, 0, stream>>>(bp, bias, out);
}